// Round 1
// baseline (124.423 us; speedup 1.0000x reference)
//
#include <hip/hip_runtime.h>

// Problem constants: B=16, T=2048, D=512, HD=64, causal single-head attention.
#define NB   16
#define NT   2048
#define ND   512
#define NHD  64

typedef __attribute__((ext_vector_type(8))) short bf16x8;   // 8 bf16 in 4 VGPRs
typedef __attribute__((ext_vector_type(4))) short bf16x4;   // 8-byte pack
typedef __attribute__((ext_vector_type(4))) float f32x4;

static __device__ __forceinline__ short f2bf(float f) {
    // round-to-nearest-even f32 -> bf16 (no NaN handling needed; data is finite)
    union { float f; unsigned u; } x{f};
    unsigned r = (x.u + 0x7fffu + ((x.u >> 16) & 1u)) >> 16;
    return (short)r;
}

// ---------------------------------------------------------------------------
// Kernel 1: transpose W (f32 [512][64]) -> Wt (bf16 [3][64][512])
// One thread per output element; writes coalesced along k.
// ---------------------------------------------------------------------------
__global__ __launch_bounds__(256) void wtrans_kernel(
    const float* __restrict__ Wq, const float* __restrict__ Wk,
    const float* __restrict__ Wv, short* __restrict__ wt) {
    int tid = blockIdx.x * 256 + threadIdx.x;       // 0 .. 3*64*512-1
    int k = tid & (ND - 1);
    int c = (tid >> 9) & (NHD - 1);
    int m = tid >> 15;                              // 0..2
    const float* W = (m == 0) ? Wq : (m == 1) ? Wk : Wv;
    wt[tid] = f2bf(W[k * NHD + c]);                 // wt[(m*64+c)*512+k]
}

// ---------------------------------------------------------------------------
// Kernel 2: QKV projection.  C[32768,64] = X[32768,512] @ W[512,64] for q,k,v.
// Grid 512 blocks x 256 thr (4 waves); wave owns 16 rows x 64 cols x 3 mats.
// A-frags straight from global x (8 consecutive f32 -> bf16), B-frags 16B
// loads from Wt (L2-resident, 196KB total). No LDS, no barriers.
// q,k stored row-major bf16 [32768][64]; v stored transposed [16][64][2048].
// ---------------------------------------------------------------------------
__global__ __launch_bounds__(256) void qkv_proj_kernel(
    const float* __restrict__ x, const short* __restrict__ wt,
    short* __restrict__ qws, short* __restrict__ kws, short* __restrict__ vtws) {
    int lane = threadIdx.x & 63;
    int wv   = threadIdx.x >> 6;        // 0..3
    int q16  = lane & 15;               // A row / B col within 16
    int g    = lane >> 4;               // 0..3 (K-group)
    long R0  = (long)blockIdx.x * 64 + wv * 16;     // token row base of wave
    const float* xrow = x + (R0 + q16) * ND;

    f32x4 acc[3][4];
#pragma unroll
    for (int m = 0; m < 3; ++m)
#pragma unroll
        for (int cb = 0; cb < 4; ++cb) acc[m][cb] = (f32x4){0.f, 0.f, 0.f, 0.f};

#pragma unroll 4
    for (int ch = 0; ch < 16; ++ch) {               // K chunks of 32
        const f32x4* xp = (const f32x4*)(xrow + ch * 32 + g * 8);
        f32x4 a0 = xp[0], a1 = xp[1];
        bf16x8 a;
#pragma unroll
        for (int j = 0; j < 4; ++j) { a[j] = f2bf(a0[j]); a[4 + j] = f2bf(a1[j]); }
#pragma unroll
        for (int m = 0; m < 3; ++m) {
#pragma unroll
            for (int cb = 0; cb < 4; ++cb) {
                bf16x8 b = *(const bf16x8*)(wt +
                    ((m * 64 + cb * 16 + q16) * ND + ch * 32 + g * 8));
                acc[m][cb] = __builtin_amdgcn_mfma_f32_16x16x32_bf16(
                    a, b, acc[m][cb], 0, 0, 0);
            }
        }
    }

    // Epilogue. D layout: row = g*4 + r (token), col = cb*16 + q16.
    int b    = (int)(R0 >> 11);         // R0 / 2048
    int tloc = (int)(R0 & 2047) + g * 4;
#pragma unroll
    for (int cb = 0; cb < 4; ++cb) {
        int col = cb * 16 + q16;
#pragma unroll
        for (int r = 0; r < 4; ++r) {
            long tok = R0 + g * 4 + r;
            qws[tok * NHD + col] = f2bf(acc[0][cb][r]);
            kws[tok * NHD + col] = f2bf(acc[1][cb][r]);
        }
        bf16x4 vp;
#pragma unroll
        for (int r = 0; r < 4; ++r) vp[r] = f2bf(acc[2][cb][r]);
        *(bf16x4*)(vtws + ((long)(b * 64 + col) * NT + tloc)) = vp;
    }
}

// ---------------------------------------------------------------------------
// Kernel 3: causal flash attention, bf16 MFMA.
// Grid: 16 batches x 32 q-tiles (QBLK=64); 4 waves, each owns 16 q rows.
// Swapped QK^T (mfma(K,Q)) -> lane holds scores of ONE q row; softmax is
// 16 in-lane values + shfl_xor(16/32). PV uses V^T tile (A) x P (B).
// LDS tiles XOR-swizzled: byte ^= (row&7)<<4 (G4 fix for 128B-row tiles).
// ---------------------------------------------------------------------------
__global__ __launch_bounds__(256) void attn_kernel(
    const short* __restrict__ qws, const short* __restrict__ kws,
    const short* __restrict__ vtws, float* __restrict__ out) {
    int qt   = blockIdx.x & 31;
    int b    = blockIdx.x >> 5;
    int tid  = threadIdx.x;
    int lane = tid & 63;
    int wv   = tid >> 6;
    int qcol = lane & 15;       // this lane's q (column of S^T)
    int g    = lane >> 4;

    __shared__ __align__(16) short Kt[64 * 64];     // [key][hd]   8KB swizzled
    __shared__ __align__(16) short Vt[64 * 64];     // [hd][key]   8KB swizzled
    __shared__ __align__(16) short Pl[4][16 * 64];  // per-wave P [q][key] 8KB

    int q0   = qt * 64;
    int qrow = q0 + wv * 16 + qcol;

    // Q fragments (B-operand of swapped QK^T): lane holds Q[qrow][c*32+g*8+j]
    const short* qbase = qws + (long)(b * NT + qrow) * NHD;
    bf16x8 qf0 = *(const bf16x8*)(qbase + g * 8);
    bf16x8 qf1 = *(const bf16x8*)(qbase + 32 + g * 8);

    f32x4 o[4];
#pragma unroll
    for (int h = 0; h < 4; ++h) o[h] = (f32x4){0.f, 0.f, 0.f, 0.f};
    float m_run = -1e30f, l_run = 0.f;

    int nkv = qt + 1;
    for (int kvi = 0; kvi < nkv; ++kvi) {
        int kv0 = kvi * 64;
        // ---- stage K tile [64][64] and V^T tile [64][64] (swizzled) ----
#pragma unroll
        for (int i = 0; i < 2; ++i) {
            int flat = tid + i * 256;               // 0..511
            int row = flat >> 3, seg = flat & 7;
            bf16x8 kd = *(const bf16x8*)(kws + (long)(b * NT + kv0 + row) * NHD + seg * 8);
            *(bf16x8*)((char*)Kt + row * 128 + ((seg * 16) ^ ((row & 7) << 4))) = kd;
            bf16x8 vd = *(const bf16x8*)(vtws + (long)(b * 64 + row) * NT + kv0 + seg * 8);
            *(bf16x8*)((char*)Vt + row * 128 + ((seg * 16) ^ ((row & 7) << 4))) = vd;
        }
        __syncthreads();

        // ---- S^T = K · Q^T : 4 key-subtiles x 2 HD chunks ----
        f32x4 s[4];
#pragma unroll
        for (int ks = 0; ks < 4; ++ks) {
            int krow = ks * 16 + qcol;              // LDS row = key in tile
            bf16x8 kf0 = *(const bf16x8*)((char*)Kt + krow * 128 +
                          ((g * 16) ^ ((krow & 7) << 4)));
            bf16x8 kf1 = *(const bf16x8*)((char*)Kt + krow * 128 +
                          ((64 + g * 16) ^ ((krow & 7) << 4)));
            f32x4 z = (f32x4){0.f, 0.f, 0.f, 0.f};
            z = __builtin_amdgcn_mfma_f32_16x16x32_bf16(kf0, qf0, z, 0, 0, 0);
            s[ks] = __builtin_amdgcn_mfma_f32_16x16x32_bf16(kf1, qf1, z, 0, 0, 0);
        }

        // ---- mask + online softmax (per-lane q row) ----
        float sv[16];
        float mloc = -1e30f;
#pragma unroll
        for (int ks = 0; ks < 4; ++ks) {
#pragma unroll
            for (int r = 0; r < 4; ++r) {
                float t = s[ks][r] * 0.125f;        // 1/sqrt(64)
                int key = kv0 + ks * 16 + g * 4 + r;
                if (key > qrow) t = -1e30f;         // causal mask
                sv[ks * 4 + r] = t;
                mloc = fmaxf(mloc, t);
            }
        }
        mloc = fmaxf(mloc, __shfl_xor(mloc, 16));
        mloc = fmaxf(mloc, __shfl_xor(mloc, 32));
        float m_new = fmaxf(m_run, mloc);
        float alpha = __expf(m_run - m_new);        // 0 on first tile
        float lloc = 0.f;
        short pb[16];
#pragma unroll
        for (int i = 0; i < 16; ++i) {
            float p = __expf(sv[i] - m_new);
            lloc += p;
            pb[i] = f2bf(p);
        }
        lloc += __shfl_xor(lloc, 16);
        lloc += __shfl_xor(lloc, 32);
        l_run = l_run * alpha + lloc;
        m_run = m_new;
#pragma unroll
        for (int h = 0; h < 4; ++h) o[h] *= alpha;

        // ---- write P (bf16) to per-wave LDS [q][key], swizzled ----
#pragma unroll
        for (int ks = 0; ks < 4; ++ks) {
            bf16x4 pk;
#pragma unroll
            for (int r = 0; r < 4; ++r) pk[r] = pb[ks * 4 + r];
            *(bf16x4*)((char*)Pl[wv] + qcol * 128 +
                       ((ks * 32 + g * 8) ^ ((qcol & 7) << 4))) = pk;
        }

        // ---- O^T += V^T · P : 4 hd-subtiles x 2 key-chunks ----
#pragma unroll
        for (int h = 0; h < 4; ++h) {
#pragma unroll
            for (int kc = 0; kc < 2; ++kc) {
                int vrow = h * 16 + qcol;           // LDS row = hd
                bf16x8 vf = *(const bf16x8*)((char*)Vt + vrow * 128 +
                             ((kc * 64 + g * 16) ^ ((vrow & 7) << 4)));
                bf16x8 pf = *(const bf16x8*)((char*)Pl[wv] + qcol * 128 +
                             ((kc * 64 + g * 16) ^ ((qcol & 7) << 4)));
                o[h] = __builtin_amdgcn_mfma_f32_16x16x32_bf16(vf, pf, o[h], 0, 0, 0);
            }
        }
        __syncthreads();    // protect K/V tiles before restage
    }

    // ---- epilogue: O^T row = g*4+r (hd), col = qcol (q); divide by l ----
    float inv = 1.0f / l_run;
    long obase = (long)(b * NT + qrow) * NHD;
#pragma unroll
    for (int h = 0; h < 4; ++h) {
        f32x4 r = o[h] * inv;
        *(f32x4*)(out + obase + h * 16 + g * 4) = r;
    }
}

// ---------------------------------------------------------------------------
extern "C" void kernel_launch(void* const* d_in, const int* in_sizes, int n_in,
                              void* d_out, int out_size, void* d_ws, size_t ws_size,
                              hipStream_t stream) {
    const float* x  = (const float*)d_in[0];
    const float* Wq = (const float*)d_in[1];
    const float* Wk = (const float*)d_in[2];
    const float* Wv = (const float*)d_in[3];
    float* out = (float*)d_out;

    short* ws   = (short*)d_ws;
    short* qws  = ws;                           // [32768][64] bf16
    short* kws  = ws + (long)32768 * 64;        // [32768][64] bf16
    short* vtws = ws + (long)2 * 32768 * 64;    // [16][64][2048] bf16
    short* wt   = ws + (long)3 * 32768 * 64;    // [3][64][512] bf16

    wtrans_kernel<<<384, 256, 0, stream>>>(Wq, Wk, Wv, wt);
    qkv_proj_kernel<<<512, 256, 0, stream>>>(x, wt, qws, kws, vtws);
    attn_kernel<<<512, 256, 0, stream>>>(qws, kws, vtws, out);
}

// Round 2
// 111.329 us; speedup vs baseline: 1.1176x; 1.1176x over previous
//
#include <hip/hip_runtime.h>
#include <hip/hip_bf16.h>

// Problem constants: B=16, T=2048, D=512, HD=64, causal single-head attention.
#define NB   16
#define NT   2048
#define ND   512
#define NHD  64
// (1/sqrt(64)) * log2(e): folded into q so softmax uses exp2 directly.
#define QSCALE 0.1803368801111204f

typedef __attribute__((ext_vector_type(8))) short bf16x8;   // 8 bf16 in 4 VGPRs
typedef __attribute__((ext_vector_type(4))) short bf16x4;   // 8-byte pack
typedef __attribute__((ext_vector_type(4))) float f32x4;

static __device__ __forceinline__ short f2bf(float f) {
    union { __hip_bfloat16 h; short s; } u;
    u.h = __float2bfloat16(f);   // RNE; compiler can pair into v_cvt_pk_bf16_f32
    return u.s;
}

// ---------------------------------------------------------------------------
// Kernel 1: transpose W (f32 [512][64]) -> Wt (bf16 [3][64][512])
// ---------------------------------------------------------------------------
__global__ __launch_bounds__(256) void wtrans_kernel(
    const float* __restrict__ Wq, const float* __restrict__ Wk,
    const float* __restrict__ Wv, short* __restrict__ wt) {
    int tid = blockIdx.x * 256 + threadIdx.x;       // 0 .. 3*64*512-1
    int k = tid & (ND - 1);
    int c = (tid >> 9) & (NHD - 1);
    int m = tid >> 15;                              // 0..2
    const float* W = (m == 0) ? Wq : (m == 1) ? Wk : Wv;
    wt[tid] = f2bf(W[k * NHD + c]);                 // wt[(m*64+c)*512+k]
}

// ---------------------------------------------------------------------------
// Kernel 2: QKV projection, matrix-split for occupancy.
// Grid 1536 blocks (tg = bid/3 token-group, m = bid%3 matrix) x 4 waves.
// Wave: 16 tokens x 64 cols of ONE matrix -> only 16 acc VGPRs, 3x the waves
// of round-1 (which was latency-bound at 21% occupancy / 3.4% MfmaUtil).
// Adjacent blocks (3tg..3tg+2) share the same x rows -> L2/L3 absorb reuse.
// q is pre-scaled by QSCALE so attention softmax is pure exp2.
// ---------------------------------------------------------------------------
__global__ __launch_bounds__(256) void qkv_proj_kernel(
    const float* __restrict__ x, const short* __restrict__ wt,
    short* __restrict__ qws, short* __restrict__ kws, short* __restrict__ vtws) {
    int lane = threadIdx.x & 63;
    int wv   = threadIdx.x >> 6;        // 0..3
    int q16  = lane & 15;               // A row / B col within 16
    int g    = lane >> 4;               // 0..3 (K-group)
    int bid  = blockIdx.x;
    int tg   = bid / 3;                 // 0..511
    int m    = bid - tg * 3;            // 0..2
    long R0  = (long)tg * 64 + wv * 16; // token row base of wave
    const float* xrow = x + (R0 + q16) * ND;
    const short* wbase = wt + m * NHD * ND;

    f32x4 acc[4];
#pragma unroll
    for (int cb = 0; cb < 4; ++cb) acc[cb] = (f32x4){0.f, 0.f, 0.f, 0.f};

#pragma unroll 4
    for (int ch = 0; ch < 16; ++ch) {               // K chunks of 32
        const f32x4* xp = (const f32x4*)(xrow + ch * 32 + g * 8);
        f32x4 a0 = xp[0], a1 = xp[1];
        bf16x8 a;
#pragma unroll
        for (int j = 0; j < 4; ++j) { a[j] = f2bf(a0[j]); a[4 + j] = f2bf(a1[j]); }
#pragma unroll
        for (int cb = 0; cb < 4; ++cb) {
            bf16x8 bb = *(const bf16x8*)(wbase + (cb * 16 + q16) * ND + ch * 32 + g * 8);
            acc[cb] = __builtin_amdgcn_mfma_f32_16x16x32_bf16(a, bb, acc[cb], 0, 0, 0);
        }
    }

    // Epilogue. D layout: row (token) = g*4 + r, col = cb*16 + q16.
    int b    = (int)(R0 >> 11);
    int tloc = (int)(R0 & 2047) + g * 4;
    if (m == 2) {                                   // v stored transposed [64][2048]
#pragma unroll
        for (int cb = 0; cb < 4; ++cb) {
            bf16x4 vp;
#pragma unroll
            for (int r = 0; r < 4; ++r) vp[r] = f2bf(acc[cb][r]);
            *(bf16x4*)(vtws + (long)(b * NHD + cb * 16 + q16) * NT + tloc) = vp;
        }
    } else {
        short* dst = (m == 0) ? qws : kws;
        float sc   = (m == 0) ? QSCALE : 1.0f;
#pragma unroll
        for (int cb = 0; cb < 4; ++cb) {
            int col = cb * 16 + q16;
#pragma unroll
            for (int r = 0; r < 4; ++r)
                dst[(R0 + g * 4 + r) * NHD + col] = f2bf(acc[cb][r] * sc);
        }
    }
}

// ---------------------------------------------------------------------------
// Kernel 3: causal flash attention, bf16 MFMA, double-buffered K/V (T14).
// Block remap balances per-CU work: blocks bid and bid+256 have qt summing
// to 31 (heavy tiles first). One __syncthreads per KV iteration.
// Swapped QK^T (mfma(K,Q)) -> lane owns one q row; softmax in-register.
// LDS XOR-swizzle byte ^= (row&7)<<4 throughout (G4).
// ---------------------------------------------------------------------------
__global__ __launch_bounds__(256) void attn_kernel(
    const short* __restrict__ qws, const short* __restrict__ kws,
    const short* __restrict__ vtws, float* __restrict__ out) {
    int bid  = blockIdx.x;
    int hh   = bid >> 8;                // 0 = heavy half, 1 = light half
    int u    = bid & 255;
    int b    = u >> 4;
    int qt   = hh ? (u & 15) : (31 - (u & 15));
    int tid  = threadIdx.x;
    int lane = tid & 63;
    int wv   = tid >> 6;
    int qcol = lane & 15;               // this lane's q (column of S^T)
    int g    = lane >> 4;

    __shared__ __align__(16) short Kt[2][64 * 64];  // [key][hd]  2x8KB swizzled
    __shared__ __align__(16) short Vt[2][64 * 64];  // [hd][key]  2x8KB swizzled
    __shared__ __align__(16) short Pl[4][16 * 64];  // per-wave P [q][key] 8KB

    int qrow = qt * 64 + wv * 16 + qcol;

    // Q fragments (B-operand of swapped QK^T); q already holds QSCALE.
    const short* qbase = qws + (long)(b * NT + qrow) * NHD;
    bf16x8 qf0 = *(const bf16x8*)(qbase + g * 8);
    bf16x8 qf1 = *(const bf16x8*)(qbase + 32 + g * 8);

    const short* kbase = kws + (long)b * NT * NHD;
    const short* vbase = vtws + (long)b * NHD * NT;
    int srow = tid >> 3;                // 0..31 (stage row; +32 for 2nd half)
    int sseg = tid & 7;

    bf16x8 kd0, kd1, vd0, vd1;          // prefetch registers (T14)
    auto LOADT = [&](int kv0) {
        kd0 = *(const bf16x8*)(kbase + (long)(kv0 + srow) * NHD + sseg * 8);
        kd1 = *(const bf16x8*)(kbase + (long)(kv0 + srow + 32) * NHD + sseg * 8);
        vd0 = *(const bf16x8*)(vbase + (long)srow * NT + kv0 + sseg * 8);
        vd1 = *(const bf16x8*)(vbase + (long)(srow + 32) * NT + kv0 + sseg * 8);
    };
    auto WRITET = [&](int buf) {
        int o0 = srow * 128 + ((sseg * 16) ^ ((srow & 7) << 4));
        int o1 = o0 + 32 * 128;         // (srow+32)&7 == srow&7
        *(bf16x8*)((char*)Kt[buf] + o0) = kd0;
        *(bf16x8*)((char*)Kt[buf] + o1) = kd1;
        *(bf16x8*)((char*)Vt[buf] + o0) = vd0;
        *(bf16x8*)((char*)Vt[buf] + o1) = vd1;
    };

    f32x4 o[4];
#pragma unroll
    for (int h = 0; h < 4; ++h) o[h] = (f32x4){0.f, 0.f, 0.f, 0.f};
    float m_run = -1e30f, l_run = 0.f;

    LOADT(0);
    WRITET(0);
    __syncthreads();

    int nkv = qt + 1;
    for (int kvi = 0; kvi < nkv; ++kvi) {
        int  cur = kvi & 1;
        bool pre = (kvi + 1 < nkv);
        if (pre) LOADT((kvi + 1) * 64);             // in flight during compute

        int kv0 = kvi * 64;
        // ---- S^T = K · Q^T ----
        f32x4 s[4];
        __builtin_amdgcn_s_setprio(1);
#pragma unroll
        for (int ks = 0; ks < 4; ++ks) {
            int krow = ks * 16 + qcol;
            const char* kb = (const char*)Kt[cur] + krow * 128;
            int sw = (krow & 7) << 4;
            bf16x8 kf0 = *(const bf16x8*)(kb + ((g * 16) ^ sw));
            bf16x8 kf1 = *(const bf16x8*)(kb + ((64 + g * 16) ^ sw));
            f32x4 z = (f32x4){0.f, 0.f, 0.f, 0.f};
            z = __builtin_amdgcn_mfma_f32_16x16x32_bf16(kf0, qf0, z, 0, 0, 0);
            s[ks] = __builtin_amdgcn_mfma_f32_16x16x32_bf16(kf1, qf1, z, 0, 0, 0);
        }
        __builtin_amdgcn_s_setprio(0);

        // ---- online softmax (scores already in log2 domain) ----
        float sv[16];
        float mloc = m_run;
        if (kvi == qt) {                            // only diagonal tile masks
#pragma unroll
            for (int ks = 0; ks < 4; ++ks)
#pragma unroll
                for (int r = 0; r < 4; ++r) {
                    float t = s[ks][r];
                    if (kv0 + ks * 16 + g * 4 + r > qrow) t = -1e30f;
                    sv[ks * 4 + r] = t;
                    mloc = fmaxf(mloc, t);
                }
        } else {
#pragma unroll
            for (int ks = 0; ks < 4; ++ks)
#pragma unroll
                for (int r = 0; r < 4; ++r) {
                    float t = s[ks][r];
                    sv[ks * 4 + r] = t;
                    mloc = fmaxf(mloc, t);
                }
        }
        mloc = fmaxf(mloc, __shfl_xor(mloc, 16));
        mloc = fmaxf(mloc, __shfl_xor(mloc, 32));
        float alpha = exp2f(m_run - mloc);          // 0 on first tile
        m_run = mloc;
        float lloc = 0.f;
        short pb[16];
#pragma unroll
        for (int i = 0; i < 16; ++i) {
            float p = exp2f(sv[i] - m_run);
            lloc += p;
            pb[i] = f2bf(p);
        }
        lloc += __shfl_xor(lloc, 16);
        lloc += __shfl_xor(lloc, 32);
        l_run = l_run * alpha + lloc;
#pragma unroll
        for (int h = 0; h < 4; ++h) o[h] *= alpha;

        // ---- P -> per-wave LDS [q][key] (swizzled) ----
#pragma unroll
        for (int ks = 0; ks < 4; ++ks) {
            bf16x4 pk;
#pragma unroll
            for (int r = 0; r < 4; ++r) pk[r] = pb[ks * 4 + r];
            *(bf16x4*)((char*)Pl[wv] + qcol * 128 +
                       ((ks * 32 + g * 8) ^ ((qcol & 7) << 4))) = pk;
        }

        // ---- O^T += V^T · P ----
        __builtin_amdgcn_s_setprio(1);
#pragma unroll
        for (int h = 0; h < 4; ++h) {
#pragma unroll
            for (int kc = 0; kc < 2; ++kc) {
                int vrow = h * 16 + qcol;
                bf16x8 vf = *(const bf16x8*)((char*)Vt[cur] + vrow * 128 +
                             ((kc * 64 + g * 16) ^ ((vrow & 7) << 4)));
                bf16x8 pf = *(const bf16x8*)((char*)Pl[wv] + qcol * 128 +
                             ((kc * 64 + g * 16) ^ ((qcol & 7) << 4)));
                o[h] = __builtin_amdgcn_mfma_f32_16x16x32_bf16(vf, pf, o[h], 0, 0, 0);
            }
        }
        __builtin_amdgcn_s_setprio(0);

        if (pre) { WRITET(cur ^ 1); __syncthreads(); }
    }

    // ---- epilogue: O^T row = hd, col = q; divide by l ----
    float inv = 1.0f / l_run;
    long obase = (long)(b * NT + qrow) * NHD;
#pragma unroll
    for (int h = 0; h < 4; ++h) {
        f32x4 r = o[h] * inv;
        *(f32x4*)(out + obase + h * 16 + g * 4) = r;
    }
}

// ---------------------------------------------------------------------------
extern "C" void kernel_launch(void* const* d_in, const int* in_sizes, int n_in,
                              void* d_out, int out_size, void* d_ws, size_t ws_size,
                              hipStream_t stream) {
    const float* x  = (const float*)d_in[0];
    const float* Wq = (const float*)d_in[1];
    const float* Wk = (const float*)d_in[2];
    const float* Wv = (const float*)d_in[3];
    float* out = (float*)d_out;

    short* ws   = (short*)d_ws;
    short* qws  = ws;                           // [32768][64] bf16 (pre-scaled)
    short* kws  = ws + (long)32768 * 64;        // [32768][64] bf16
    short* vtws = ws + (long)2 * 32768 * 64;    // [16][64][2048] bf16
    short* wt   = ws + (long)3 * 32768 * 64;    // [3][64][512] bf16

    wtrans_kernel<<<384, 256, 0, stream>>>(Wq, Wk, Wv, wt);
    qkv_proj_kernel<<<1536, 256, 0, stream>>>(x, wt, qws, kws, vtws);
    attn_kernel<<<512, 256, 0, stream>>>(qws, kws, vtws, out);
}

// Round 3
// 60.679 us; speedup vs baseline: 2.0505x; 1.8347x over previous
//
#include <hip/hip_runtime.h>
#include <hip/hip_bf16.h>

// Problem constants: B=16, T=2048, D=512, HD=64, causal single-head attention.
#define NB   16
#define NT   2048
#define ND   512
#define NHD  64
// (1/sqrt(64)) * log2(e): folded into q so attention softmax uses exp2 directly.
#define QSCALE 0.1803368801111204f

typedef __attribute__((ext_vector_type(8))) short bf16x8;   // 8 bf16 in 4 VGPRs
typedef __attribute__((ext_vector_type(4))) short bf16x4;   // 8-byte pack
typedef __attribute__((ext_vector_type(4))) float f32x4;

static __device__ __forceinline__ short f2bf(float f) {
    union { __hip_bfloat16 h; short s; } u;
    u.h = __float2bfloat16(f);   // RNE; pairs into v_cvt_pk_bf16_f32
    return u.s;
}

// ---------------------------------------------------------------------------
// Kernel 1: transpose W (f32 [512][64]) -> Wt (bf16 [3][64][512])
// ---------------------------------------------------------------------------
__global__ __launch_bounds__(256) void wtrans_kernel(
    const float* __restrict__ Wq, const float* __restrict__ Wk,
    const float* __restrict__ Wv, short* __restrict__ wt) {
    int tid = blockIdx.x * 256 + threadIdx.x;       // 0 .. 3*64*512-1
    int k = tid & (ND - 1);
    int c = (tid >> 9) & (NHD - 1);
    int m = tid >> 15;                              // 0..2
    const float* W = (m == 0) ? Wq : (m == 1) ? Wk : Wv;
    wt[tid] = f2bf(W[k * NHD + c]);                 // wt[(m*64+c)*512+k]
}

// ---------------------------------------------------------------------------
// Kernel 2: QKV projection as LDS-tiled GEMM. C[32768,192] = X[32768,512]·W.
// Grid 512 blocks (BM=64 tokens) x 256 thr (4 waves, 2M x 2N over 64x192).
// K-loop: 8 steps of BK=64. Per step: reg-stage X (f32->bf16, coalesced
// 256B segments) + W slice (128B segments) into XOR-swizzled LDS, then
// 24 MFMAs/wave from ds_read_b128. Next step's loads issued before compute
// (T14 async split). Round-2 failure mode was every load fragmenting into
// 16x64B scattered requests -> request-count serialized at 71us.
// ---------------------------------------------------------------------------
__global__ __launch_bounds__(256, 4) void qkv_gemm_kernel(
    const float* __restrict__ x, const short* __restrict__ wt,
    short* __restrict__ qws, short* __restrict__ kws, short* __restrict__ vtws) {
    int t    = threadIdx.x;
    int lane = t & 63;
    int wv   = t >> 6;
    int q16  = lane & 15;
    int g    = lane >> 4;
    int wm   = wv >> 1, wn = wv & 1;
    long R0  = (long)blockIdx.x * 64;

    __shared__ __align__(16) short Xt[64 * 64];     // [token][k] 8KB swizzled
    __shared__ __align__(16) short Wl[192 * 64];    // [col][k]  24KB swizzled

    // staging thread assignment
    int xrow = t >> 4, xquad = t & 15;              // X: 4 rounds of 16 rows
    int wrow = t >> 3, wseg = t & 7;                // W: 6 rounds of 32 rows

    const float* xg = x + (R0 + xrow) * ND + xquad * 4;
    const short* wg = wt + wrow * ND + wseg * 8;

    f32x4 xr[4];
    bf16x8 wr[6];
    auto LOAD = [&](int ch) {
#pragma unroll
        for (int i = 0; i < 4; ++i)
            xr[i] = *(const f32x4*)(xg + (long)i * 16 * ND + ch * 64);
#pragma unroll
        for (int i = 0; i < 6; ++i)
            wr[i] = *(const bf16x8*)(wg + (long)i * 32 * ND + ch * 64);
    };
    auto STORE_LDS = [&]() {
#pragma unroll
        for (int i = 0; i < 4; ++i) {
            bf16x4 c;
#pragma unroll
            for (int j = 0; j < 4; ++j) c[j] = f2bf(xr[i][j]);
            int row = i * 16 + xrow;
            *(bf16x4*)((char*)Xt + row * 128 +
                       (((xquad >> 1) * 16) ^ ((row & 7) << 4)) + (xquad & 1) * 8) = c;
        }
#pragma unroll
        for (int i = 0; i < 6; ++i) {
            int row = i * 32 + wrow;
            *(bf16x8*)((char*)Wl + row * 128 + ((wseg * 16) ^ ((row & 7) << 4))) = wr[i];
        }
    };

    f32x4 acc[2][6];
#pragma unroll
    for (int mi = 0; mi < 2; ++mi)
#pragma unroll
        for (int ni = 0; ni < 6; ++ni) acc[mi][ni] = (f32x4){0.f, 0.f, 0.f, 0.f};

    LOAD(0);
    for (int ch = 0; ch < 8; ++ch) {
        STORE_LDS();                    // vmcnt wait on current loads + cvt
        if (ch + 1 < 8) LOAD(ch + 1);   // in flight during compute (T14)
        __syncthreads();
        __builtin_amdgcn_s_setprio(1);
#pragma unroll
        for (int kk = 0; kk < 2; ++kk) {
            bf16x8 a[2];
#pragma unroll
            for (int mi = 0; mi < 2; ++mi) {
                int row = wm * 32 + mi * 16 + q16;
                a[mi] = *(const bf16x8*)((char*)Xt + row * 128 +
                         ((kk * 64 + g * 16) ^ ((row & 7) << 4)));
            }
#pragma unroll
            for (int ni = 0; ni < 6; ++ni) {
                int row = wn * 96 + ni * 16 + q16;
                bf16x8 b = *(const bf16x8*)((char*)Wl + row * 128 +
                            ((kk * 64 + g * 16) ^ ((row & 7) << 4)));
                acc[0][ni] = __builtin_amdgcn_mfma_f32_16x16x32_bf16(a[0], b, acc[0][ni], 0, 0, 0);
                acc[1][ni] = __builtin_amdgcn_mfma_f32_16x16x32_bf16(a[1], b, acc[1][ni], 0, 0, 0);
            }
        }
        __builtin_amdgcn_s_setprio(0);
        __syncthreads();
    }

    // Epilogue. D frag: row(token) = g*4+r, col = lane&15 within 16-block.
    int b     = (int)(R0 >> 11);
    int tloc0 = (int)(R0 & 2047);
#pragma unroll
    for (int mi = 0; mi < 2; ++mi) {
        long tok0 = R0 + wm * 32 + mi * 16 + g * 4;
#pragma unroll
        for (int ni = 0; ni < 6; ++ni) {
            int col = wn * 96 + ni * 16 + q16;
            int m = col >> 6, c64 = col & 63;       // uniform per (wn,ni)
            if (m == 0) {
#pragma unroll
                for (int r = 0; r < 4; ++r)
                    qws[(tok0 + r) * NHD + c64] = f2bf(acc[mi][ni][r] * QSCALE);
            } else if (m == 1) {
#pragma unroll
                for (int r = 0; r < 4; ++r)
                    kws[(tok0 + r) * NHD + c64] = f2bf(acc[mi][ni][r]);
            } else {
                bf16x4 vp;
#pragma unroll
                for (int r = 0; r < 4; ++r) vp[r] = f2bf(acc[mi][ni][r]);
                *(bf16x4*)(vtws + (long)(b * NHD + c64) * NT +
                           tloc0 + wm * 32 + mi * 16 + g * 4) = vp;
            }
        }
    }
}

// ---------------------------------------------------------------------------
// Kernel 3: causal flash attention, bf16 MFMA, double-buffered K/V (T14).
// Block remap balances per-CU work: blocks bid and bid+256 have qt summing
// to 31 (heavy tiles first). One __syncthreads per KV iteration.
// Swapped QK^T (mfma(K,Q)) -> lane owns one q row; softmax in-register.
// LDS XOR-swizzle byte ^= (row&7)<<4 throughout (G4).
// ---------------------------------------------------------------------------
__global__ __launch_bounds__(256) void attn_kernel(
    const short* __restrict__ qws, const short* __restrict__ kws,
    const short* __restrict__ vtws, float* __restrict__ out) {
    int bid  = blockIdx.x;
    int hh   = bid >> 8;                // 0 = heavy half, 1 = light half
    int u    = bid & 255;
    int b    = u >> 4;
    int qt   = hh ? (u & 15) : (31 - (u & 15));
    int tid  = threadIdx.x;
    int lane = tid & 63;
    int wv   = tid >> 6;
    int qcol = lane & 15;               // this lane's q (column of S^T)
    int g    = lane >> 4;

    __shared__ __align__(16) short Kt[2][64 * 64];  // [key][hd]  2x8KB swizzled
    __shared__ __align__(16) short Vt[2][64 * 64];  // [hd][key]  2x8KB swizzled
    __shared__ __align__(16) short Pl[4][16 * 64];  // per-wave P [q][key] 8KB

    int qrow = qt * 64 + wv * 16 + qcol;

    // Q fragments (B-operand of swapped QK^T); q already holds QSCALE.
    const short* qbase = qws + (long)(b * NT + qrow) * NHD;
    bf16x8 qf0 = *(const bf16x8*)(qbase + g * 8);
    bf16x8 qf1 = *(const bf16x8*)(qbase + 32 + g * 8);

    const short* kbase = kws + (long)b * NT * NHD;
    const short* vbase = vtws + (long)b * NHD * NT;
    int srow = tid >> 3;                // 0..31 (stage row; +32 for 2nd half)
    int sseg = tid & 7;

    bf16x8 kd0, kd1, vd0, vd1;          // prefetch registers (T14)
    auto LOADT = [&](int kv0) {
        kd0 = *(const bf16x8*)(kbase + (long)(kv0 + srow) * NHD + sseg * 8);
        kd1 = *(const bf16x8*)(kbase + (long)(kv0 + srow + 32) * NHD + sseg * 8);
        vd0 = *(const bf16x8*)(vbase + (long)srow * NT + kv0 + sseg * 8);
        vd1 = *(const bf16x8*)(vbase + (long)(srow + 32) * NT + kv0 + sseg * 8);
    };
    auto WRITET = [&](int buf) {
        int o0 = srow * 128 + ((sseg * 16) ^ ((srow & 7) << 4));
        int o1 = o0 + 32 * 128;         // (srow+32)&7 == srow&7
        *(bf16x8*)((char*)Kt[buf] + o0) = kd0;
        *(bf16x8*)((char*)Kt[buf] + o1) = kd1;
        *(bf16x8*)((char*)Vt[buf] + o0) = vd0;
        *(bf16x8*)((char*)Vt[buf] + o1) = vd1;
    };

    f32x4 o[4];
#pragma unroll
    for (int h = 0; h < 4; ++h) o[h] = (f32x4){0.f, 0.f, 0.f, 0.f};
    float m_run = -1e30f, l_run = 0.f;

    LOADT(0);
    WRITET(0);
    __syncthreads();

    int nkv = qt + 1;
    for (int kvi = 0; kvi < nkv; ++kvi) {
        int  cur = kvi & 1;
        bool pre = (kvi + 1 < nkv);
        if (pre) LOADT((kvi + 1) * 64);             // in flight during compute

        int kv0 = kvi * 64;
        // ---- S^T = K · Q^T ----
        f32x4 s[4];
        __builtin_amdgcn_s_setprio(1);
#pragma unroll
        for (int ks = 0; ks < 4; ++ks) {
            int krow = ks * 16 + qcol;
            const char* kb = (const char*)Kt[cur] + krow * 128;
            int sw = (krow & 7) << 4;
            bf16x8 kf0 = *(const bf16x8*)(kb + ((g * 16) ^ sw));
            bf16x8 kf1 = *(const bf16x8*)(kb + ((64 + g * 16) ^ sw));
            f32x4 z = (f32x4){0.f, 0.f, 0.f, 0.f};
            z = __builtin_amdgcn_mfma_f32_16x16x32_bf16(kf0, qf0, z, 0, 0, 0);
            s[ks] = __builtin_amdgcn_mfma_f32_16x16x32_bf16(kf1, qf1, z, 0, 0, 0);
        }
        __builtin_amdgcn_s_setprio(0);

        // ---- online softmax (scores already in log2 domain) ----
        float sv[16];
        float mloc = m_run;
        if (kvi == qt) {                            // only diagonal tile masks
#pragma unroll
            for (int ks = 0; ks < 4; ++ks)
#pragma unroll
                for (int r = 0; r < 4; ++r) {
                    float t = s[ks][r];
                    if (kv0 + ks * 16 + g * 4 + r > qrow) t = -1e30f;
                    sv[ks * 4 + r] = t;
                    mloc = fmaxf(mloc, t);
                }
        } else {
#pragma unroll
            for (int ks = 0; ks < 4; ++ks)
#pragma unroll
                for (int r = 0; r < 4; ++r) {
                    float t = s[ks][r];
                    sv[ks * 4 + r] = t;
                    mloc = fmaxf(mloc, t);
                }
        }
        mloc = fmaxf(mloc, __shfl_xor(mloc, 16));
        mloc = fmaxf(mloc, __shfl_xor(mloc, 32));
        float alpha = exp2f(m_run - mloc);          // 0 on first tile
        m_run = mloc;
        float lloc = 0.f;
        short pb[16];
#pragma unroll
        for (int i = 0; i < 16; ++i) {
            float p = exp2f(sv[i] - m_run);
            lloc += p;
            pb[i] = f2bf(p);
        }
        lloc += __shfl_xor(lloc, 16);
        lloc += __shfl_xor(lloc, 32);
        l_run = l_run * alpha + lloc;
#pragma unroll
        for (int h = 0; h < 4; ++h) o[h] *= alpha;

        // ---- P -> per-wave LDS [q][key] (swizzled) ----
#pragma unroll
        for (int ks = 0; ks < 4; ++ks) {
            bf16x4 pk;
#pragma unroll
            for (int r = 0; r < 4; ++r) pk[r] = pb[ks * 4 + r];
            *(bf16x4*)((char*)Pl[wv] + qcol * 128 +
                       ((ks * 32 + g * 8) ^ ((qcol & 7) << 4))) = pk;
        }

        // ---- O^T += V^T · P ----
        __builtin_amdgcn_s_setprio(1);
#pragma unroll
        for (int h = 0; h < 4; ++h) {
#pragma unroll
            for (int kc = 0; kc < 2; ++kc) {
                int vrow = h * 16 + qcol;
                bf16x8 vf = *(const bf16x8*)((char*)Vt[cur] + vrow * 128 +
                             ((kc * 64 + g * 16) ^ ((vrow & 7) << 4)));
                bf16x8 pf = *(const bf16x8*)((char*)Pl[wv] + qcol * 128 +
                             ((kc * 64 + g * 16) ^ ((qcol & 7) << 4)));
                o[h] = __builtin_amdgcn_mfma_f32_16x16x32_bf16(vf, pf, o[h], 0, 0, 0);
            }
        }
        __builtin_amdgcn_s_setprio(0);

        if (pre) { WRITET(cur ^ 1); __syncthreads(); }
    }

    // ---- epilogue: O^T row = hd, col = q; divide by l ----
    float inv = 1.0f / l_run;
    long obase = (long)(b * NT + qrow) * NHD;
#pragma unroll
    for (int h = 0; h < 4; ++h) {
        f32x4 r = o[h] * inv;
        *(f32x4*)(out + obase + h * 16 + g * 4) = r;
    }
}

// ---------------------------------------------------------------------------
extern "C" void kernel_launch(void* const* d_in, const int* in_sizes, int n_in,
                              void* d_out, int out_size, void* d_ws, size_t ws_size,
                              hipStream_t stream) {
    const float* x  = (const float*)d_in[0];
    const float* Wq = (const float*)d_in[1];
    const float* Wk = (const float*)d_in[2];
    const float* Wv = (const float*)d_in[3];
    float* out = (float*)d_out;

    short* ws   = (short*)d_ws;
    short* qws  = ws;                           // [32768][64] bf16 (pre-scaled)
    short* kws  = ws + (long)32768 * 64;        // [32768][64] bf16
    short* vtws = ws + (long)2 * 32768 * 64;    // [16][64][2048] bf16
    short* wt   = ws + (long)3 * 32768 * 64;    // [3][64][512] bf16

    wtrans_kernel<<<384, 256, 0, stream>>>(Wq, Wk, Wv, wt);
    qkv_gemm_kernel<<<512, 256, 0, stream>>>(x, wt, qws, kws, vtws);
    attn_kernel<<<512, 256, 0, stream>>>(qws, kws, vtws, out);
}

// Round 4
// 59.232 us; speedup vs baseline: 2.1006x; 1.0244x over previous
//
#include <hip/hip_runtime.h>
#include <hip/hip_bf16.h>

// Problem constants: B=16, T=2048, D=512, HD=64, causal single-head attention.
#define NB   16
#define NT   2048
#define ND   512
#define NHD  64
// (1/sqrt(64)) * log2(e): folded into q so attention softmax uses exp2 directly.
#define QSCALE 0.1803368801111204f
// defer-max threshold in log2 domain (~= 8 nats); P bounded by 2^11.5, bf16-safe.
#define DEFER_TH 11.5f

typedef __attribute__((ext_vector_type(8))) short bf16x8;   // 8 bf16 in 4 VGPRs
typedef __attribute__((ext_vector_type(4))) short bf16x4;   // 8-byte pack
typedef __attribute__((ext_vector_type(4))) float f32x4;

static __device__ __forceinline__ short f2bf(float f) {
    union { __hip_bfloat16 h; short s; } u;
    u.h = __float2bfloat16(f);   // RNE; pairs into v_cvt_pk_bf16_f32
    return u.s;
}

// ---------------------------------------------------------------------------
// Kernel 1: transpose W (f32 [512][64]) -> Wt (bf16 [3][64][512])
// ---------------------------------------------------------------------------
__global__ __launch_bounds__(256) void wtrans_kernel(
    const float* __restrict__ Wq, const float* __restrict__ Wk,
    const float* __restrict__ Wv, short* __restrict__ wt) {
    int tid = blockIdx.x * 256 + threadIdx.x;       // 0 .. 3*64*512-1
    int k = tid & (ND - 1);
    int c = (tid >> 9) & (NHD - 1);
    int m = tid >> 15;                              // 0..2
    const float* W = (m == 0) ? Wq : (m == 1) ? Wk : Wv;
    wt[tid] = f2bf(W[k * NHD + c]);                 // wt[(m*64+c)*512+k]
}

// ---------------------------------------------------------------------------
// Kernel 2: QKV projection as LDS-tiled GEMM. C[32768,192] = X[32768,512]·W.
// (unchanged from round 3: ~15us, near its 64MB-x-read floor of ~10us)
// ---------------------------------------------------------------------------
__global__ __launch_bounds__(256, 4) void qkv_gemm_kernel(
    const float* __restrict__ x, const short* __restrict__ wt,
    short* __restrict__ qws, short* __restrict__ kws, short* __restrict__ vtws) {
    int t    = threadIdx.x;
    int lane = t & 63;
    int q16  = lane & 15;
    int g    = lane >> 4;
    int wv   = t >> 6;
    int wm   = wv >> 1, wn = wv & 1;
    long R0  = (long)blockIdx.x * 64;

    __shared__ __align__(16) short Xt[64 * 64];     // [token][k] 8KB swizzled
    __shared__ __align__(16) short Wl[192 * 64];    // [col][k]  24KB swizzled

    int xrow = t >> 4, xquad = t & 15;              // X: 4 rounds of 16 rows
    int wrow = t >> 3, wseg = t & 7;                // W: 6 rounds of 32 rows

    const float* xg = x + (R0 + xrow) * ND + xquad * 4;
    const short* wg = wt + wrow * ND + wseg * 8;

    f32x4 xr[4];
    bf16x8 wr[6];
    auto LOAD = [&](int ch) {
#pragma unroll
        for (int i = 0; i < 4; ++i)
            xr[i] = *(const f32x4*)(xg + (long)i * 16 * ND + ch * 64);
#pragma unroll
        for (int i = 0; i < 6; ++i)
            wr[i] = *(const bf16x8*)(wg + (long)i * 32 * ND + ch * 64);
    };
    auto STORE_LDS = [&]() {
#pragma unroll
        for (int i = 0; i < 4; ++i) {
            bf16x4 c;
#pragma unroll
            for (int j = 0; j < 4; ++j) c[j] = f2bf(xr[i][j]);
            int row = i * 16 + xrow;
            *(bf16x4*)((char*)Xt + row * 128 +
                       (((xquad >> 1) * 16) ^ ((row & 7) << 4)) + (xquad & 1) * 8) = c;
        }
#pragma unroll
        for (int i = 0; i < 6; ++i) {
            int row = i * 32 + wrow;
            *(bf16x8*)((char*)Wl + row * 128 + ((wseg * 16) ^ ((row & 7) << 4))) = wr[i];
        }
    };

    f32x4 acc[2][6];
#pragma unroll
    for (int mi = 0; mi < 2; ++mi)
#pragma unroll
        for (int ni = 0; ni < 6; ++ni) acc[mi][ni] = (f32x4){0.f, 0.f, 0.f, 0.f};

    LOAD(0);
    for (int ch = 0; ch < 8; ++ch) {
        STORE_LDS();
        if (ch + 1 < 8) LOAD(ch + 1);   // in flight during compute (T14)
        __syncthreads();
        __builtin_amdgcn_s_setprio(1);
#pragma unroll
        for (int kk = 0; kk < 2; ++kk) {
            bf16x8 a[2];
#pragma unroll
            for (int mi = 0; mi < 2; ++mi) {
                int row = wm * 32 + mi * 16 + q16;
                a[mi] = *(const bf16x8*)((char*)Xt + row * 128 +
                         ((kk * 64 + g * 16) ^ ((row & 7) << 4)));
            }
#pragma unroll
            for (int ni = 0; ni < 6; ++ni) {
                int row = wn * 96 + ni * 16 + q16;
                bf16x8 b = *(const bf16x8*)((char*)Wl + row * 128 +
                            ((kk * 64 + g * 16) ^ ((row & 7) << 4)));
                acc[0][ni] = __builtin_amdgcn_mfma_f32_16x16x32_bf16(a[0], b, acc[0][ni], 0, 0, 0);
                acc[1][ni] = __builtin_amdgcn_mfma_f32_16x16x32_bf16(a[1], b, acc[1][ni], 0, 0, 0);
            }
        }
        __builtin_amdgcn_s_setprio(0);
        __syncthreads();
    }

    int b     = (int)(R0 >> 11);
    int tloc0 = (int)(R0 & 2047);
#pragma unroll
    for (int mi = 0; mi < 2; ++mi) {
        long tok0 = R0 + wm * 32 + mi * 16 + g * 4;
#pragma unroll
        for (int ni = 0; ni < 6; ++ni) {
            int col = wn * 96 + ni * 16 + q16;
            int m = col >> 6, c64 = col & 63;       // uniform per (wn,ni)
            if (m == 0) {
#pragma unroll
                for (int r = 0; r < 4; ++r)
                    qws[(tok0 + r) * NHD + c64] = f2bf(acc[mi][ni][r] * QSCALE);
            } else if (m == 1) {
#pragma unroll
                for (int r = 0; r < 4; ++r)
                    kws[(tok0 + r) * NHD + c64] = f2bf(acc[mi][ni][r]);
            } else {
                bf16x4 vp;
#pragma unroll
                for (int r = 0; r < 4; ++r) vp[r] = f2bf(acc[mi][ni][r]);
                *(bf16x4*)(vtws + (long)(b * NHD + c64) * NT +
                           tloc0 + wm * 32 + mi * 16 + g * 4) = vp;
            }
        }
    }
}

// ---------------------------------------------------------------------------
// Kernel 3: causal flash attention PARTIAL, KV-split x2 for occupancy.
// Round-3 profile: MfmaUtil 7.7 / VALUBusy 33 / Occ 11% -> latency-bound
// serial chain with only 2 blocks/CU. Now 1024 blocks (s = kv-half) -> 4
// blocks/CU = 16 waves/CU. Each block emits UNNORMALIZED O^T partial + per-
// row (m,l) in log2 domain; merge_kernel combines the two halves.
// Swapped QK^T (lane owns a q-row), XOR-swizzled LDS, reg-prefetch (T14),
// defer-max rescale skip (T13).
// ---------------------------------------------------------------------------
__global__ __launch_bounds__(256) void attn_kernel(
    const short* __restrict__ qws, const short* __restrict__ kws,
    const short* __restrict__ vtws, float* __restrict__ Opart,
    float* __restrict__ ml) {
    int bid  = blockIdx.x;
    int s    = bid >> 9;                // kv half
    int bb   = bid & 511;
    int hh   = bb >> 8;                 // 0 = heavy half of qt range
    int u    = bb & 255;
    int b    = u >> 4;
    int qt   = hh ? (u & 15) : (31 - (u & 15));
    int tid  = threadIdx.x;
    int lane = tid & 63;
    int wv   = tid >> 6;
    int qcol = lane & 15;               // this lane's q (column of S^T)
    int g    = lane >> 4;

    __shared__ __align__(16) short Kt[2][64 * 64];  // [key][hd]  2x8KB swizzled
    __shared__ __align__(16) short Vt[2][64 * 64];  // [hd][key]  2x8KB swizzled
    __shared__ __align__(16) short Pl[4][16 * 64];  // per-wave P [q][key] 8KB

    int qrow = qt * 64 + wv * 16 + qcol;

    // Q fragments (B-operand of swapped QK^T); q already holds QSCALE*log2e.
    const short* qbase = qws + (long)(b * NT + qrow) * NHD;
    bf16x8 qf0 = *(const bf16x8*)(qbase + g * 8);
    bf16x8 qf1 = *(const bf16x8*)(qbase + 32 + g * 8);

    const short* kbase = kws + (long)b * NT * NHD;
    const short* vbase = vtws + (long)b * NHD * NT;
    int srow = tid >> 3;                // 0..31 (stage row; +32 for 2nd half)
    int sseg = tid & 7;

    bf16x8 kd0, kd1, vd0, vd1;          // prefetch registers (T14)
    auto LOADT = [&](int kv0) {
        kd0 = *(const bf16x8*)(kbase + (long)(kv0 + srow) * NHD + sseg * 8);
        kd1 = *(const bf16x8*)(kbase + (long)(kv0 + srow + 32) * NHD + sseg * 8);
        vd0 = *(const bf16x8*)(vbase + (long)srow * NT + kv0 + sseg * 8);
        vd1 = *(const bf16x8*)(vbase + (long)(srow + 32) * NT + kv0 + sseg * 8);
    };
    auto WRITET = [&](int buf) {
        int o0 = srow * 128 + ((sseg * 16) ^ ((srow & 7) << 4));
        int o1 = o0 + 32 * 128;         // (srow+32)&7 == srow&7
        *(bf16x8*)((char*)Kt[buf] + o0) = kd0;
        *(bf16x8*)((char*)Kt[buf] + o1) = kd1;
        *(bf16x8*)((char*)Vt[buf] + o0) = vd0;
        *(bf16x8*)((char*)Vt[buf] + o1) = vd1;
    };

    f32x4 o[4];
#pragma unroll
    for (int h = 0; h < 4; ++h) o[h] = (f32x4){0.f, 0.f, 0.f, 0.f};
    float m_run = -1e30f, l_run = 0.f;

    int n   = qt + 1;
    int tlo = s ? (n >> 1) : 0;         // this block's kv-tile range
    int thi = s ? n : (n >> 1);         // diag tile always in s=1

    if (tlo < thi) {                    // uniform per block
        LOADT(tlo * 64);
        WRITET(0);
        __syncthreads();

        for (int kvi = tlo; kvi < thi; ++kvi) {
            int  cur = (kvi - tlo) & 1;
            bool pre = (kvi + 1 < thi);
            if (pre) LOADT((kvi + 1) * 64);         // in flight during compute

            int kv0 = kvi * 64;
            // ---- S^T = K · Q^T ----
            f32x4 sreg[4];
            __builtin_amdgcn_s_setprio(1);
#pragma unroll
            for (int ks = 0; ks < 4; ++ks) {
                int krow = ks * 16 + qcol;
                const char* kb = (const char*)Kt[cur] + krow * 128;
                int sw = (krow & 7) << 4;
                bf16x8 kf0 = *(const bf16x8*)(kb + ((g * 16) ^ sw));
                bf16x8 kf1 = *(const bf16x8*)(kb + ((64 + g * 16) ^ sw));
                f32x4 z = (f32x4){0.f, 0.f, 0.f, 0.f};
                z = __builtin_amdgcn_mfma_f32_16x16x32_bf16(kf0, qf0, z, 0, 0, 0);
                sreg[ks] = __builtin_amdgcn_mfma_f32_16x16x32_bf16(kf1, qf1, z, 0, 0, 0);
            }
            __builtin_amdgcn_s_setprio(0);

            // ---- mask (diagonal tile only) + tile max ----
            float sv[16];
            float tmax = -1e30f;
            if (kvi == qt) {
#pragma unroll
                for (int ks = 0; ks < 4; ++ks)
#pragma unroll
                    for (int r = 0; r < 4; ++r) {
                        float tv = sreg[ks][r];
                        if (kv0 + ks * 16 + g * 4 + r > qrow) tv = -1e30f;
                        sv[ks * 4 + r] = tv;
                        tmax = fmaxf(tmax, tv);
                    }
            } else {
#pragma unroll
                for (int ks = 0; ks < 4; ++ks)
#pragma unroll
                    for (int r = 0; r < 4; ++r) {
                        float tv = sreg[ks][r];
                        sv[ks * 4 + r] = tv;
                        tmax = fmaxf(tmax, tv);
                    }
            }
            tmax = fmaxf(tmax, __shfl_xor(tmax, 16));
            tmax = fmaxf(tmax, __shfl_xor(tmax, 32));

            // ---- T13 defer-max: rescale only if max grew past threshold ----
            if (__ballot(tmax > m_run + DEFER_TH)) {
                float mnew = fmaxf(m_run, tmax);
                float alpha = exp2f(m_run - mnew);  // 0 on first tile
                l_run *= alpha;
#pragma unroll
                for (int h = 0; h < 4; ++h) o[h] *= alpha;
                m_run = mnew;
            }

            float lloc = 0.f;
            short pb[16];
#pragma unroll
            for (int i = 0; i < 16; ++i) {
                float p = exp2f(sv[i] - m_run);
                lloc += p;
                pb[i] = f2bf(p);
            }
            lloc += __shfl_xor(lloc, 16);
            lloc += __shfl_xor(lloc, 32);
            l_run += lloc;

            // ---- P -> per-wave LDS [q][key] (swizzled) ----
#pragma unroll
            for (int ks = 0; ks < 4; ++ks) {
                bf16x4 pk;
#pragma unroll
                for (int r = 0; r < 4; ++r) pk[r] = pb[ks * 4 + r];
                *(bf16x4*)((char*)Pl[wv] + qcol * 128 +
                           ((ks * 32 + g * 8) ^ ((qcol & 7) << 4))) = pk;
            }

            // ---- O^T += V^T · P ----
            __builtin_amdgcn_s_setprio(1);
#pragma unroll
            for (int h = 0; h < 4; ++h) {
#pragma unroll
                for (int kc = 0; kc < 2; ++kc) {
                    int vrow = h * 16 + qcol;
                    bf16x8 vf = *(const bf16x8*)((char*)Vt[cur] + vrow * 128 +
                                 ((kc * 64 + g * 16) ^ ((vrow & 7) << 4)));
                    bf16x8 pf = *(const bf16x8*)((char*)Pl[wv] + qcol * 128 +
                                 ((kc * 64 + g * 16) ^ ((qcol & 7) << 4)));
                    o[h] = __builtin_amdgcn_mfma_f32_16x16x32_bf16(vf, pf, o[h], 0, 0, 0);
                }
            }
            __builtin_amdgcn_s_setprio(0);

            if (pre) { WRITET(cur ^ 1); __syncthreads(); }
        }
    }

    // ---- epilogue: UNNORMALIZED partial O^T + (m,l) per q-row ----
    int  sbqt  = s * 512 + b * 32 + qt;
    long pbase = ((long)sbqt * 64 + wv * 16 + qcol) * 64;
#pragma unroll
    for (int h = 0; h < 4; ++h)
        *(f32x4*)(Opart + pbase + h * 16 + g * 4) = o[h];
    if (g == 0) {
        ml[(sbqt * 2) * 64 + wv * 16 + qcol]     = m_run;
        ml[(sbqt * 2 + 1) * 64 + wv * 16 + qcol] = l_run;
    }
}

// ---------------------------------------------------------------------------
// Kernel 4: merge the two KV-half partials.
// out = (e0*O0 + e1*O1) / (e0*l0 + e1*l1), ei = 2^(mi - max(m0,m1)).
// Empty half (qt=0,s=0) has m=-1e30 -> e=0 kills its (finite-garbage) O.
// ---------------------------------------------------------------------------
__global__ __launch_bounds__(256) void merge_kernel(
    const float* __restrict__ Opart, const float* __restrict__ ml,
    float* __restrict__ out) {
    int idx  = blockIdx.x * 256 + threadIdx.x;      // 0 .. 524287
    int hd4  = idx & 15;
    int ridx = idx >> 4;                            // bqt*64 + qr
    int bqt  = ridx >> 6;
    int qr   = ridx & 63;

    float m0 = ml[(bqt * 2) * 64 + qr];
    float l0 = ml[(bqt * 2 + 1) * 64 + qr];
    float m1 = ml[((512 + bqt) * 2) * 64 + qr];
    float l1 = ml[((512 + bqt) * 2 + 1) * 64 + qr];
    float mm = fmaxf(m0, m1);
    float e0 = exp2f(m0 - mm);
    float e1 = exp2f(m1 - mm);
    float inv = 1.0f / (e0 * l0 + e1 * l1);

    f32x4 O0 = *(const f32x4*)(Opart + (long)ridx * 64 + hd4 * 4);
    f32x4 O1 = *(const f32x4*)(Opart + ((long)(512 * 64) + ridx) * 64 + hd4 * 4);
    f32x4 r  = (O0 * e0 + O1 * e1) * inv;

    int b = bqt >> 5, qt = bqt & 31;
    *(f32x4*)(out + ((long)(b << 11) + qt * 64 + qr) * 64 + hd4 * 4) = r;
}

// ---------------------------------------------------------------------------
extern "C" void kernel_launch(void* const* d_in, const int* in_sizes, int n_in,
                              void* d_out, int out_size, void* d_ws, size_t ws_size,
                              hipStream_t stream) {
    const float* x  = (const float*)d_in[0];
    const float* Wq = (const float*)d_in[1];
    const float* Wk = (const float*)d_in[2];
    const float* Wv = (const float*)d_in[3];
    float* out = (float*)d_out;

    // ws layout: floats first (16B aligned), then bf16 buffers.
    float* fb    = (float*)d_ws;
    float* Opart = fb;                              // 2*512*64*64 = 4,194,304 f (16MB)
    float* mlb   = fb + (long)4194304;              // 2*512*2*64  = 131,072 f (0.5MB)
    short* sb    = (short*)(fb + 4194304 + 131072);
    short* qws   = sb;                              // [32768][64] bf16 (pre-scaled)
    short* kws   = sb + (long)2097152;              // [32768][64] bf16
    short* vtws  = sb + (long)2 * 2097152;          // [16][64][2048] bf16
    short* wt    = sb + (long)3 * 2097152;          // [3][64][512] bf16

    wtrans_kernel<<<384, 256, 0, stream>>>(Wq, Wk, Wv, wt);
    qkv_gemm_kernel<<<512, 256, 0, stream>>>(x, wt, qws, kws, vtws);
    attn_kernel<<<1024, 256, 0, stream>>>(qws, kws, vtws, Opart, mlb);
    merge_kernel<<<2048, 256, 0, stream>>>(Opart, mlb, out);
}